// Round 8
// baseline (163.628 us; speedup 1.0000x reference)
//
#include <hip/hip_runtime.h>
#include <hip/hip_bf16.h>

#define N_NODES 10000
#define N_EDGES 100000

typedef __attribute__((ext_vector_type(8))) short short8;
typedef __attribute__((ext_vector_type(4))) short shortx4;
typedef __attribute__((ext_vector_type(4))) float f32x4;

static __device__ inline short bf16bits(float x) {
    union { __bf16 b; short s; } u;
    u.b = (__bf16)x;
    return u.s;
}
static __device__ inline unsigned short bf16u(float x) {
    union { __bf16 b; unsigned short s; } u;
    u.b = (__bf16)x;
    return u.s;
}
static __device__ inline float bf2f(unsigned short us) {
    union { unsigned int u; float f; } c;
    c.u = ((unsigned int)us) << 16;
    return c.f;
}
static __device__ inline short8 cvt8(const float* f) {
    short8 r;
#pragma unroll
    for (int j = 0; j < 8; ++j) r[j] = bf16bits(f[j]);
    return r;
}

// ---------------------------------------------------------------------------
// Combined prep kernel, 65 blocks x 1024 threads:
//  block 0:      zero deg in LDS -> histogram receivers (LDS atomics) ->
//                exclusive scan -> write off[10001] + cursor[10000]
//  blocks 1..64: fold L1s/L1v into Wgen -> Wc (bf16, MFMA B-frag order) and
//                L2s/L2v into WS0/WS1 -> WB0/WB1 (bf16 B-frag, K=512)
// Edge scale: rnorm*alpha*lnorm = 1/128. Node scale: snorm*lnorm = 1/128.
// ---------------------------------------------------------------------------
__global__ __launch_bounds__(1024) void prep_kernel(
    const float* __restrict__ Wgen, const float* __restrict__ L1s,
    const float* __restrict__ L1v, const float* __restrict__ WS0,
    const float* __restrict__ WS1, const float* __restrict__ L2s,
    const float* __restrict__ L2v, const int* __restrict__ edge_index,
    unsigned short* __restrict__ Wc, unsigned short* __restrict__ WB0,
    unsigned short* __restrict__ WB1, int* __restrict__ off,
    int* __restrict__ cursor) {
    __shared__ int sdeg[N_NODES];   // 40 KB
    __shared__ int part[1024];      //  4 KB
    if (blockIdx.x == 0) {
        int t = threadIdx.x;
        for (int i = t; i < N_NODES; i += 1024) sdeg[i] = 0;
        __syncthreads();
        for (int e = t; e < N_EDGES; e += 1024)
            atomicAdd(&sdeg[edge_index[N_EDGES + e]], 1);
        __syncthreads();
        int base = t * 10;
        int s = 0;
#pragma unroll
        for (int i = 0; i < 10; ++i) {
            int idx = base + i;
            if (idx < N_NODES) s += sdeg[idx];
        }
        part[t] = s;
        __syncthreads();
        for (int d = 1; d < 1024; d <<= 1) {
            int v = (t >= d) ? part[t - d] : 0;
            __syncthreads();
            part[t] += v;
            __syncthreads();
        }
        int run = part[t] - s;
#pragma unroll
        for (int i = 0; i < 10; ++i) {
            int idx = base + i;
            if (idx < N_NODES) {
                off[idx] = run;
                cursor[idx] = run;
                run += sdeg[idx];
            }
        }
        if (t == 1023) off[N_NODES] = run;
        return;
    }

    const float S = 1.0f / 128.0f;
    int tid = (blockIdx.x - 1) * 1024 + threadIdx.x;   // 0..65535
    if (tid < 32768) {
        // Edge weights, B-fragment order: flat = ((nt*8 + ks)*64 + lane)*8 + j
        int j = tid & 7;
        int lane = (tid >> 3) & 63;
        int ks = (tid >> 9) & 7;
        int nt = tid >> 12;
        int col = nt * 16 + (lane & 15);
        int u = (lane >> 4) * 8 + j;
        int r = ks;
        int p, c2;
        const float* M;
        float sc = S;
        if (col < 32)      { p = 0; M = L1s; c2 = col; }
        else if (col < 64) { p = 1; M = L1v; c2 = col - 32; }
        else if (col < 96) { p = 2; M = L1v; c2 = col - 64; }
        else               { p = 3; M = L1s; c2 = col - 96; sc = S * 0.57735026918962576f; }
        const float* wg = Wgen + r * 4096 + p * 1024 + u * 32;
        float acc = 0.f;
#pragma unroll
        for (int w = 0; w < 32; ++w) acc += wg[w] * M[w * 32 + c2];
        Wc[tid] = bf16u(acc * sc);
    } else {
        int idx = tid - 32768;
        int table = idx >> 14;
        int r14 = idx & 16383;          // ((nt*16+ks)*64+lane)*8+j
        int j = r14 & 7;
        int lane = (r14 >> 3) & 63;
        int ks = (r14 >> 9) & 15;
        int k = ks * 32 + (lane >> 4) * 8 + j;   // 0..511
        int u = k >> 4, v = k & 15;
        int w = ((r14 >> 13) & 1) * 16 + (lane & 15);
        const float* WS = table ? WS1 : WS0;
        const float* L2 = table ? L2v : L2s;
        const float* src = WS + u * 512 + v * 32;
        float acc = 0.f;
#pragma unroll
        for (int x = 0; x < 32; ++x) acc += src[x] * L2[x * 32 + w];
        unsigned short val = bf16u(acc * S);
        if (table) WB1[r14] = val; else WB0[r14] = val;
    }
}

// ---------------------------------------------------------------------------
// Edge kernel v5.1: R6 pipelined structure; slot allocation inline via
// atomicAdd(cursor[rcv], 1) — GUARDED to lane<16 (q==0). R7 bug: all 4
// q-groups allocated (4x per edge), overflowing cursor ranges; only q=0's
// values are consumed by the shfl epilogue (rows 0..15 = lanes 0..15).
// Msg layout interleaved: Msg[slot*128 + col*4 + comp], shortx4 stores.
// ---------------------------------------------------------------------------
__global__ __launch_bounds__(256) void edge_kernel(
    const float* __restrict__ node_feats, const float* __restrict__ edge_attrs,
    const float* __restrict__ edge_feats, const int* __restrict__ edge_index,
    const unsigned short* __restrict__ Wc, int* __restrict__ cursor,
    unsigned short* __restrict__ Msg) {
    __shared__ short8 sW8[4096];  // 64 KB, B-fragment order
    {
        const short8* src = (const short8*)Wc;
        for (int i = threadIdx.x; i < 4096; i += 256) sW8[i] = src[i];
    }
    __syncthreads();

    const int lane = threadIdx.x & 63;
    const int m = lane & 15, q = lane >> 4;
    const int wave = (blockIdx.x * 256 + threadIdx.x) >> 6;
    const int stride = gridDim.x * 4;
    const int NT = N_EDGES / 16;

    int tile = wave;
    if (tile >= NT) return;

    float xsC[8], xvC[24], efC[8];
    f32x4 eaC;
    int slC = 0;

    // prologue: load current tile's state + allocate slot (q==0 lanes only)
    {
        int e = tile * 16 + m;
        int snd = edge_index[e];
        if (lane < 16) slC = atomicAdd(&cursor[edge_index[N_EDGES + e]], 1);
        const float* g = node_feats + snd * 128;
        *(f32x4*)&xsC[0] = *(const f32x4*)(g + q * 8);
        *(f32x4*)&xsC[4] = *(const f32x4*)(g + q * 8 + 4);
#pragma unroll
        for (int i = 0; i < 6; ++i)
            *(f32x4*)&xvC[i * 4] = *(const f32x4*)(g + 32 + q * 24 + i * 4);
        *(f32x4*)&efC[0] = *(const f32x4*)(edge_feats + e * 8);
        *(f32x4*)&efC[4] = *(const f32x4*)(edge_feats + e * 8 + 4);
        eaC = *(const f32x4*)(edge_attrs + e * 4);
    }

    while (tile < NT) {
        const int tn = tile + stride;
        const bool hasN = tn < NT;

        // ---- prefetch next tile's state (hidden behind current compute)
        float xsN[8], xvN[24], efN[8];
        f32x4 eaN;
        int slN = 0;
        if (hasN) {
            int en = tn * 16 + m;
            int sndN = edge_index[en];
            if (lane < 16) slN = atomicAdd(&cursor[edge_index[N_EDGES + en]], 1);
            const float* gN = node_feats + sndN * 128;
            *(f32x4*)&xsN[0] = *(const f32x4*)(gN + q * 8);
            *(f32x4*)&xsN[4] = *(const f32x4*)(gN + q * 8 + 4);
#pragma unroll
            for (int i = 0; i < 6; ++i)
                *(f32x4*)&xvN[i * 4] = *(const f32x4*)(gN + 32 + q * 24 + i * 4);
            *(f32x4*)&efN[0] = *(const f32x4*)(edge_feats + en * 8);
            *(f32x4*)&efN[4] = *(const f32x4*)(edge_feats + en * 8 + 4);
            eaN = *(const f32x4*)(edge_attrs + en * 4);
        }

        // ---- compute current tile
        float dt[8];
        {
            float y0 = eaC.y, y1 = eaC.z, y2 = eaC.w;
#pragma unroll
            for (int j = 0; j < 8; ++j)
                dt[j] = xvC[j * 3] * y0 + xvC[j * 3 + 1] * y1 + xvC[j * 3 + 2] * y2;
        }

        f32x4 z = {0.f, 0.f, 0.f, 0.f};
        f32x4 fA[2] = {z, z}, fB[2] = {z, z}, fD[2] = {z, z};
        f32x4 fC[3][2] = {{z, z}, {z, z}, {z, z}};

#pragma unroll
        for (int ks = 0; ks < 8; ++ks) {
            float h = efC[ks];
            float t[8];
#pragma unroll
            for (int j = 0; j < 8; ++j) t[j] = h * xsC[j];
            {
                short8 a = cvt8(t);
                fA[0] = __builtin_amdgcn_mfma_f32_16x16x32_bf16(a, sW8[(0 * 8 + ks) * 64 + lane], fA[0], 0, 0, 0);
                fA[1] = __builtin_amdgcn_mfma_f32_16x16x32_bf16(a, sW8[(1 * 8 + ks) * 64 + lane], fA[1], 0, 0, 0);
                fB[0] = __builtin_amdgcn_mfma_f32_16x16x32_bf16(a, sW8[(2 * 8 + ks) * 64 + lane], fB[0], 0, 0, 0);
                fB[1] = __builtin_amdgcn_mfma_f32_16x16x32_bf16(a, sW8[(3 * 8 + ks) * 64 + lane], fB[1], 0, 0, 0);
            }
            {
                short8 bc0 = sW8[(4 * 8 + ks) * 64 + lane];
                short8 bc1 = sW8[(5 * 8 + ks) * 64 + lane];
#pragma unroll
                for (int c = 0; c < 3; ++c) {
#pragma unroll
                    for (int j = 0; j < 8; ++j) t[j] = h * xvC[j * 3 + c];
                    short8 a = cvt8(t);
                    fC[c][0] = __builtin_amdgcn_mfma_f32_16x16x32_bf16(a, bc0, fC[c][0], 0, 0, 0);
                    fC[c][1] = __builtin_amdgcn_mfma_f32_16x16x32_bf16(a, bc1, fC[c][1], 0, 0, 0);
                }
            }
            {
#pragma unroll
                for (int j = 0; j < 8; ++j) t[j] = h * dt[j];
                short8 a = cvt8(t);
                fD[0] = __builtin_amdgcn_mfma_f32_16x16x32_bf16(a, sW8[(6 * 8 + ks) * 64 + lane], fD[0], 0, 0, 0);
                fD[1] = __builtin_amdgcn_mfma_f32_16x16x32_bf16(a, sW8[(7 * 8 + ks) * 64 + lane], fD[1], 0, 0, 0);
            }
        }

        // ---- epilogue: shfl row-broadcast (lanes 0..15 hold edge m's ea/slot)
#pragma unroll
        for (int t4 = 0; t4 < 4; ++t4) {
            int row = q * 4 + t4;
            float ysr = __shfl(eaC.x, row);
            float y0r = __shfl(eaC.y, row);
            float y1r = __shfl(eaC.z, row);
            float y2r = __shfl(eaC.w, row);
            int dr = __shfl(slC, row);
#pragma unroll
            for (int nt = 0; nt < 2; ++nt) {
                int col = nt * 16 + m;
                float pb = fB[nt][t4];
                shortx4 pk;
                pk[0] = bf16bits(ysr * fA[nt][t4] + fD[nt][t4]);
                pk[1] = bf16bits(y0r * pb + ysr * fC[0][nt][t4]);
                pk[2] = bf16bits(y1r * pb + ysr * fC[1][nt][t4]);
                pk[3] = bf16bits(y2r * pb + ysr * fC[2][nt][t4]);
                *(shortx4*)(Msg + (size_t)dr * 128 + col * 4) = pk;
            }
        }

        // ---- rotate pipeline
        tile = tn;
        if (hasN) {
#pragma unroll
            for (int j = 0; j < 8; ++j) { xsC[j] = xsN[j]; efC[j] = efN[j]; }
#pragma unroll
            for (int j = 0; j < 24; ++j) xvC[j] = xvN[j];
            eaC = eaN;
            slC = slN;
        }
    }
}

// ---------------------------------------------------------------------------
// Fused gather + node kernel (unchanged; matches interleaved Msg layout).
// ---------------------------------------------------------------------------
__global__ __launch_bounds__(256) void node_kernel(
    const float* __restrict__ node_attrs, const unsigned short* __restrict__ Msg,
    const int* __restrict__ off, const unsigned short* __restrict__ WB0,
    const unsigned short* __restrict__ WB1, float* __restrict__ out) {
    __shared__ float sM[16][129];
    __shared__ float sAt[16][17];
    int n0 = blockIdx.x * 16;

    int nl = threadIdx.x >> 4;
    int cg = threadIdx.x & 15;
    int n = n0 + nl;
    int s0 = off[n], s1 = off[n + 1];
    float acc[8];
#pragma unroll
    for (int j = 0; j < 8; ++j) acc[j] = 0.f;
    for (int s = s0; s < s1; ++s) {
        f32x4 raw = *(const f32x4*)(Msg + (size_t)s * 128 + cg * 8);
        const unsigned short* us = (const unsigned short*)&raw;
#pragma unroll
        for (int j = 0; j < 8; ++j) acc[j] += bf2f(us[j]);
    }
#pragma unroll
    for (int j = 0; j < 8; ++j)
        sM[nl][(j & 3) * 32 + cg * 2 + (j >> 2)] = acc[j];
    sAt[nl][cg] = node_attrs[n * 16 + cg];
    __syncthreads();

    int p = threadIdx.x >> 6;
    int lane = threadIdx.x & 63;
    int m = lane & 15, q = lane >> 4;
    const unsigned short* WB = (p == 0) ? WB0 : WB1;
    int chb = p * 32;
    f32x4 z = {0.f, 0.f, 0.f, 0.f};
    f32x4 D0 = z, D1 = z;
#pragma unroll
    for (int ks = 0; ks < 16; ++ks) {
        int kb = ks * 32 + q * 8;
        float t[8];
#pragma unroll
        for (int j = 0; j < 8; ++j) {
            int k = kb + j;
            t[j] = sM[m][chb + (k >> 4)] * sAt[m][k & 15];
        }
        short8 a = cvt8(t);
        short8 b0 = *(const short8*)(WB + (ks * 64 + lane) * 8);
        short8 b1 = *(const short8*)(WB + ((16 + ks) * 64 + lane) * 8);
        D0 = __builtin_amdgcn_mfma_f32_16x16x32_bf16(a, b0, D0, 0, 0, 0);
        D1 = __builtin_amdgcn_mfma_f32_16x16x32_bf16(a, b1, D1, 0, 0, 0);
    }

#pragma unroll
    for (int t4 = 0; t4 < 4; ++t4) {
        int nl2 = q * 4 + t4;
        int nn = n0 + nl2;
        if (p == 0) {
            out[nn * 128 + m]      = sM[nl2][m] + D0[t4];
            out[nn * 128 + 16 + m] = sM[nl2][16 + m] + D1[t4];
        } else {
            int i = p - 1;
            out[nn * 128 + 32 + m * 3 + i]        = sM[nl2][chb + m] + D0[t4];
            out[nn * 128 + 32 + (16 + m) * 3 + i] = sM[nl2][chb + 16 + m] + D1[t4];
        }
    }
}

extern "C" void kernel_launch(void* const* d_in, const int* in_sizes, int n_in,
                              void* d_out, int out_size, void* d_ws, size_t ws_size,
                              hipStream_t stream) {
    (void)in_sizes; (void)n_in; (void)out_size; (void)ws_size;
    const float* node_attrs = (const float*)d_in[0];
    const float* node_feats = (const float*)d_in[1];
    const float* edge_attrs = (const float*)d_in[2];
    const float* edge_feats = (const float*)d_in[3];
    const int*   edge_index = (const int*)d_in[4];
    const float* Wgen = (const float*)d_in[5];
    const float* L1s  = (const float*)d_in[6];
    const float* L1v  = (const float*)d_in[7];
    const float* WS0  = (const float*)d_in[8];
    const float* WS1  = (const float*)d_in[9];
    const float* L2s  = (const float*)d_in[10];
    const float* L2v  = (const float*)d_in[11];
    float* out = (float*)d_out;
    char* ws = (char*)d_ws;

    unsigned short* Msg = (unsigned short*)ws;                 // 25,600,000
    unsigned short* Wc  = (unsigned short*)(ws + 25600000);    //     65,536
    unsigned short* WB0 = (unsigned short*)(ws + 25665536);    //     32,768
    unsigned short* WB1 = (unsigned short*)(ws + 25698304);    //     32,768
    int* off    = (int*)(ws + 25731072);                       //     40,004
    int* cursor = (int*)(ws + 25771076);                       //     40,000

    prep_kernel<<<65, 1024, 0, stream>>>(Wgen, L1s, L1v, WS0, WS1, L2s, L2v,
                                         edge_index, Wc, WB0, WB1, off, cursor);
    edge_kernel<<<512, 256, 0, stream>>>(node_feats, edge_attrs, edge_feats,
                                         edge_index, Wc, cursor, Msg);
    node_kernel<<<625, 256, 0, stream>>>(node_attrs, Msg, off, WB0, WB1, out);
}

// Round 9
// 144.347 us; speedup vs baseline: 1.1336x; 1.1336x over previous
//
#include <hip/hip_runtime.h>
#include <hip/hip_bf16.h>

#define N_NODES 10000
#define N_EDGES 100000

typedef __attribute__((ext_vector_type(8))) short short8;
typedef __attribute__((ext_vector_type(4))) short shortx4;
typedef __attribute__((ext_vector_type(4))) float f32x4;

static __device__ inline short bf16bits(float x) {
    union { __bf16 b; short s; } u;
    u.b = (__bf16)x;
    return u.s;
}
static __device__ inline unsigned short bf16u(float x) {
    union { __bf16 b; unsigned short s; } u;
    u.b = (__bf16)x;
    return u.s;
}
static __device__ inline float bf2f(unsigned short us) {
    union { unsigned int u; float f; } c;
    c.u = ((unsigned int)us) << 16;
    return c.f;
}
static __device__ inline short8 cvt8(const float* f) {
    short8 r;
#pragma unroll
    for (int j = 0; j < 8; ++j) r[j] = bf16bits(f[j]);
    return r;
}

// ---------------------------------------------------------------------------
// Combined prep kernel, 65 blocks x 1024 threads:
//  block 0:      zero deg in LDS -> histogram receivers (int4-batched loads,
//                LDS atomics) -> exclusive scan -> off[10001] + cursor[10000]
//  blocks 1..64: fold L1s/L1v into Wgen -> Wc (bf16, MFMA B-frag order) and
//                L2s/L2v into WS0/WS1 -> WB0/WB1 (bf16 B-frag, K=512)
// R8 lesson: the scalar histogram loop was 98 serial load->atomic latency
// hops (~37 us). Batch 4 independent int4 loads per iteration -> 6 hops.
// ---------------------------------------------------------------------------
__global__ __launch_bounds__(1024) void prep_kernel(
    const float* __restrict__ Wgen, const float* __restrict__ L1s,
    const float* __restrict__ L1v, const float* __restrict__ WS0,
    const float* __restrict__ WS1, const float* __restrict__ L2s,
    const float* __restrict__ L2v, const int* __restrict__ edge_index,
    unsigned short* __restrict__ Wc, unsigned short* __restrict__ WB0,
    unsigned short* __restrict__ WB1, int* __restrict__ off,
    int* __restrict__ cursor) {
    __shared__ int sdeg[N_NODES];   // 40 KB
    __shared__ int part[1024];      //  4 KB
    if (blockIdx.x == 0) {
        int t = threadIdx.x;
        for (int i = t; i < N_NODES; i += 1024) sdeg[i] = 0;
        __syncthreads();
        // Histogram: receivers = edge_index[100000..200000) = 25000 int4s.
        // Bulk 24576 int4s: exactly 6 iterations, 4 independent loads each.
        const int4* r4 = (const int4*)(edge_index + N_EDGES);
        for (int i0 = t; i0 < 24576; i0 += 4096) {
            int4 a = r4[i0];
            int4 b = r4[i0 + 1024];
            int4 c = r4[i0 + 2048];
            int4 d = r4[i0 + 3072];
            atomicAdd(&sdeg[a.x], 1); atomicAdd(&sdeg[a.y], 1);
            atomicAdd(&sdeg[a.z], 1); atomicAdd(&sdeg[a.w], 1);
            atomicAdd(&sdeg[b.x], 1); atomicAdd(&sdeg[b.y], 1);
            atomicAdd(&sdeg[b.z], 1); atomicAdd(&sdeg[b.w], 1);
            atomicAdd(&sdeg[c.x], 1); atomicAdd(&sdeg[c.y], 1);
            atomicAdd(&sdeg[c.z], 1); atomicAdd(&sdeg[c.w], 1);
            atomicAdd(&sdeg[d.x], 1); atomicAdd(&sdeg[d.y], 1);
            atomicAdd(&sdeg[d.z], 1); atomicAdd(&sdeg[d.w], 1);
        }
        // Tail: int4s [24576, 25000)
        if (t < 424) {
            int4 v = r4[24576 + t];
            atomicAdd(&sdeg[v.x], 1); atomicAdd(&sdeg[v.y], 1);
            atomicAdd(&sdeg[v.z], 1); atomicAdd(&sdeg[v.w], 1);
        }
        __syncthreads();
        int base = t * 10;
        int s = 0;
#pragma unroll
        for (int i = 0; i < 10; ++i) {
            int idx = base + i;
            if (idx < N_NODES) s += sdeg[idx];
        }
        part[t] = s;
        __syncthreads();
        for (int d = 1; d < 1024; d <<= 1) {
            int v = (t >= d) ? part[t - d] : 0;
            __syncthreads();
            part[t] += v;
            __syncthreads();
        }
        int run = part[t] - s;
#pragma unroll
        for (int i = 0; i < 10; ++i) {
            int idx = base + i;
            if (idx < N_NODES) {
                off[idx] = run;
                cursor[idx] = run;
                run += sdeg[idx];
            }
        }
        if (t == 1023) off[N_NODES] = run;
        return;
    }

    const float S = 1.0f / 128.0f;
    int tid = (blockIdx.x - 1) * 1024 + threadIdx.x;   // 0..65535
    if (tid < 32768) {
        // Edge weights, B-fragment order: flat = ((nt*8 + ks)*64 + lane)*8 + j
        int j = tid & 7;
        int lane = (tid >> 3) & 63;
        int ks = (tid >> 9) & 7;
        int nt = tid >> 12;
        int col = nt * 16 + (lane & 15);
        int u = (lane >> 4) * 8 + j;
        int r = ks;
        int p, c2;
        const float* M;
        float sc = S;
        if (col < 32)      { p = 0; M = L1s; c2 = col; }
        else if (col < 64) { p = 1; M = L1v; c2 = col - 32; }
        else if (col < 96) { p = 2; M = L1v; c2 = col - 64; }
        else               { p = 3; M = L1s; c2 = col - 96; sc = S * 0.57735026918962576f; }
        const float* wg = Wgen + r * 4096 + p * 1024 + u * 32;
        float acc = 0.f;
#pragma unroll
        for (int w = 0; w < 32; ++w) acc += wg[w] * M[w * 32 + c2];
        Wc[tid] = bf16u(acc * sc);
    } else {
        int idx = tid - 32768;
        int table = idx >> 14;
        int r14 = idx & 16383;          // ((nt*16+ks)*64+lane)*8+j
        int j = r14 & 7;
        int lane = (r14 >> 3) & 63;
        int ks = (r14 >> 9) & 15;
        int k = ks * 32 + (lane >> 4) * 8 + j;   // 0..511
        int u = k >> 4, v = k & 15;
        int w = ((r14 >> 13) & 1) * 16 + (lane & 15);
        const float* WS = table ? WS1 : WS0;
        const float* L2 = table ? L2v : L2s;
        const float* src = WS + u * 512 + v * 32;
        float acc = 0.f;
#pragma unroll
        for (int x = 0; x < 32; ++x) acc += src[x] * L2[x * 32 + w];
        unsigned short val = bf16u(acc * S);
        if (table) WB1[r14] = val; else WB0[r14] = val;
    }
}

// ---------------------------------------------------------------------------
// Edge kernel v5.1 (unchanged from R8): pipelined tile loop; inline slot
// allocation guarded to lane<16 (q==0); shfl epilogue; interleaved Msg.
// ---------------------------------------------------------------------------
__global__ __launch_bounds__(256) void edge_kernel(
    const float* __restrict__ node_feats, const float* __restrict__ edge_attrs,
    const float* __restrict__ edge_feats, const int* __restrict__ edge_index,
    const unsigned short* __restrict__ Wc, int* __restrict__ cursor,
    unsigned short* __restrict__ Msg) {
    __shared__ short8 sW8[4096];  // 64 KB, B-fragment order
    {
        const short8* src = (const short8*)Wc;
        for (int i = threadIdx.x; i < 4096; i += 256) sW8[i] = src[i];
    }
    __syncthreads();

    const int lane = threadIdx.x & 63;
    const int m = lane & 15, q = lane >> 4;
    const int wave = (blockIdx.x * 256 + threadIdx.x) >> 6;
    const int stride = gridDim.x * 4;
    const int NT = N_EDGES / 16;

    int tile = wave;
    if (tile >= NT) return;

    float xsC[8], xvC[24], efC[8];
    f32x4 eaC;
    int slC = 0;

    {
        int e = tile * 16 + m;
        int snd = edge_index[e];
        if (lane < 16) slC = atomicAdd(&cursor[edge_index[N_EDGES + e]], 1);
        const float* g = node_feats + snd * 128;
        *(f32x4*)&xsC[0] = *(const f32x4*)(g + q * 8);
        *(f32x4*)&xsC[4] = *(const f32x4*)(g + q * 8 + 4);
#pragma unroll
        for (int i = 0; i < 6; ++i)
            *(f32x4*)&xvC[i * 4] = *(const f32x4*)(g + 32 + q * 24 + i * 4);
        *(f32x4*)&efC[0] = *(const f32x4*)(edge_feats + e * 8);
        *(f32x4*)&efC[4] = *(const f32x4*)(edge_feats + e * 8 + 4);
        eaC = *(const f32x4*)(edge_attrs + e * 4);
    }

    while (tile < NT) {
        const int tn = tile + stride;
        const bool hasN = tn < NT;

        float xsN[8], xvN[24], efN[8];
        f32x4 eaN;
        int slN = 0;
        if (hasN) {
            int en = tn * 16 + m;
            int sndN = edge_index[en];
            if (lane < 16) slN = atomicAdd(&cursor[edge_index[N_EDGES + en]], 1);
            const float* gN = node_feats + sndN * 128;
            *(f32x4*)&xsN[0] = *(const f32x4*)(gN + q * 8);
            *(f32x4*)&xsN[4] = *(const f32x4*)(gN + q * 8 + 4);
#pragma unroll
            for (int i = 0; i < 6; ++i)
                *(f32x4*)&xvN[i * 4] = *(const f32x4*)(gN + 32 + q * 24 + i * 4);
            *(f32x4*)&efN[0] = *(const f32x4*)(edge_feats + en * 8);
            *(f32x4*)&efN[4] = *(const f32x4*)(edge_feats + en * 8 + 4);
            eaN = *(const f32x4*)(edge_attrs + en * 4);
        }

        float dt[8];
        {
            float y0 = eaC.y, y1 = eaC.z, y2 = eaC.w;
#pragma unroll
            for (int j = 0; j < 8; ++j)
                dt[j] = xvC[j * 3] * y0 + xvC[j * 3 + 1] * y1 + xvC[j * 3 + 2] * y2;
        }

        f32x4 z = {0.f, 0.f, 0.f, 0.f};
        f32x4 fA[2] = {z, z}, fB[2] = {z, z}, fD[2] = {z, z};
        f32x4 fC[3][2] = {{z, z}, {z, z}, {z, z}};

#pragma unroll
        for (int ks = 0; ks < 8; ++ks) {
            float h = efC[ks];
            float t[8];
#pragma unroll
            for (int j = 0; j < 8; ++j) t[j] = h * xsC[j];
            {
                short8 a = cvt8(t);
                fA[0] = __builtin_amdgcn_mfma_f32_16x16x32_bf16(a, sW8[(0 * 8 + ks) * 64 + lane], fA[0], 0, 0, 0);
                fA[1] = __builtin_amdgcn_mfma_f32_16x16x32_bf16(a, sW8[(1 * 8 + ks) * 64 + lane], fA[1], 0, 0, 0);
                fB[0] = __builtin_amdgcn_mfma_f32_16x16x32_bf16(a, sW8[(2 * 8 + ks) * 64 + lane], fB[0], 0, 0, 0);
                fB[1] = __builtin_amdgcn_mfma_f32_16x16x32_bf16(a, sW8[(3 * 8 + ks) * 64 + lane], fB[1], 0, 0, 0);
            }
            {
                short8 bc0 = sW8[(4 * 8 + ks) * 64 + lane];
                short8 bc1 = sW8[(5 * 8 + ks) * 64 + lane];
#pragma unroll
                for (int c = 0; c < 3; ++c) {
#pragma unroll
                    for (int j = 0; j < 8; ++j) t[j] = h * xvC[j * 3 + c];
                    short8 a = cvt8(t);
                    fC[c][0] = __builtin_amdgcn_mfma_f32_16x16x32_bf16(a, bc0, fC[c][0], 0, 0, 0);
                    fC[c][1] = __builtin_amdgcn_mfma_f32_16x16x32_bf16(a, bc1, fC[c][1], 0, 0, 0);
                }
            }
            {
#pragma unroll
                for (int j = 0; j < 8; ++j) t[j] = h * dt[j];
                short8 a = cvt8(t);
                fD[0] = __builtin_amdgcn_mfma_f32_16x16x32_bf16(a, sW8[(6 * 8 + ks) * 64 + lane], fD[0], 0, 0, 0);
                fD[1] = __builtin_amdgcn_mfma_f32_16x16x32_bf16(a, sW8[(7 * 8 + ks) * 64 + lane], fD[1], 0, 0, 0);
            }
        }

#pragma unroll
        for (int t4 = 0; t4 < 4; ++t4) {
            int row = q * 4 + t4;
            float ysr = __shfl(eaC.x, row);
            float y0r = __shfl(eaC.y, row);
            float y1r = __shfl(eaC.z, row);
            float y2r = __shfl(eaC.w, row);
            int dr = __shfl(slC, row);
#pragma unroll
            for (int nt = 0; nt < 2; ++nt) {
                int col = nt * 16 + m;
                float pb = fB[nt][t4];
                shortx4 pk;
                pk[0] = bf16bits(ysr * fA[nt][t4] + fD[nt][t4]);
                pk[1] = bf16bits(y0r * pb + ysr * fC[0][nt][t4]);
                pk[2] = bf16bits(y1r * pb + ysr * fC[1][nt][t4]);
                pk[3] = bf16bits(y2r * pb + ysr * fC[2][nt][t4]);
                *(shortx4*)(Msg + (size_t)dr * 128 + col * 4) = pk;
            }
        }

        tile = tn;
        if (hasN) {
#pragma unroll
            for (int j = 0; j < 8; ++j) { xsC[j] = xsN[j]; efC[j] = efN[j]; }
#pragma unroll
            for (int j = 0; j < 24; ++j) xvC[j] = xvN[j];
            eaC = eaN;
            slC = slN;
        }
    }
}

// ---------------------------------------------------------------------------
// Fused gather + node kernel (unchanged; matches interleaved Msg layout).
// ---------------------------------------------------------------------------
__global__ __launch_bounds__(256) void node_kernel(
    const float* __restrict__ node_attrs, const unsigned short* __restrict__ Msg,
    const int* __restrict__ off, const unsigned short* __restrict__ WB0,
    const unsigned short* __restrict__ WB1, float* __restrict__ out) {
    __shared__ float sM[16][129];
    __shared__ float sAt[16][17];
    int n0 = blockIdx.x * 16;

    int nl = threadIdx.x >> 4;
    int cg = threadIdx.x & 15;
    int n = n0 + nl;
    int s0 = off[n], s1 = off[n + 1];
    float acc[8];
#pragma unroll
    for (int j = 0; j < 8; ++j) acc[j] = 0.f;
    for (int s = s0; s < s1; ++s) {
        f32x4 raw = *(const f32x4*)(Msg + (size_t)s * 128 + cg * 8);
        const unsigned short* us = (const unsigned short*)&raw;
#pragma unroll
        for (int j = 0; j < 8; ++j) acc[j] += bf2f(us[j]);
    }
#pragma unroll
    for (int j = 0; j < 8; ++j)
        sM[nl][(j & 3) * 32 + cg * 2 + (j >> 2)] = acc[j];
    sAt[nl][cg] = node_attrs[n * 16 + cg];
    __syncthreads();

    int p = threadIdx.x >> 6;
    int lane = threadIdx.x & 63;
    int m = lane & 15, q = lane >> 4;
    const unsigned short* WB = (p == 0) ? WB0 : WB1;
    int chb = p * 32;
    f32x4 z = {0.f, 0.f, 0.f, 0.f};
    f32x4 D0 = z, D1 = z;
#pragma unroll
    for (int ks = 0; ks < 16; ++ks) {
        int kb = ks * 32 + q * 8;
        float t[8];
#pragma unroll
        for (int j = 0; j < 8; ++j) {
            int k = kb + j;
            t[j] = sM[m][chb + (k >> 4)] * sAt[m][k & 15];
        }
        short8 a = cvt8(t);
        short8 b0 = *(const short8*)(WB + (ks * 64 + lane) * 8);
        short8 b1 = *(const short8*)(WB + ((16 + ks) * 64 + lane) * 8);
        D0 = __builtin_amdgcn_mfma_f32_16x16x32_bf16(a, b0, D0, 0, 0, 0);
        D1 = __builtin_amdgcn_mfma_f32_16x16x32_bf16(a, b1, D1, 0, 0, 0);
    }

#pragma unroll
    for (int t4 = 0; t4 < 4; ++t4) {
        int nl2 = q * 4 + t4;
        int nn = n0 + nl2;
        if (p == 0) {
            out[nn * 128 + m]      = sM[nl2][m] + D0[t4];
            out[nn * 128 + 16 + m] = sM[nl2][16 + m] + D1[t4];
        } else {
            int i = p - 1;
            out[nn * 128 + 32 + m * 3 + i]        = sM[nl2][chb + m] + D0[t4];
            out[nn * 128 + 32 + (16 + m) * 3 + i] = sM[nl2][chb + 16 + m] + D1[t4];
        }
    }
}

extern "C" void kernel_launch(void* const* d_in, const int* in_sizes, int n_in,
                              void* d_out, int out_size, void* d_ws, size_t ws_size,
                              hipStream_t stream) {
    (void)in_sizes; (void)n_in; (void)out_size; (void)ws_size;
    const float* node_attrs = (const float*)d_in[0];
    const float* node_feats = (const float*)d_in[1];
    const float* edge_attrs = (const float*)d_in[2];
    const float* edge_feats = (const float*)d_in[3];
    const int*   edge_index = (const int*)d_in[4];
    const float* Wgen = (const float*)d_in[5];
    const float* L1s  = (const float*)d_in[6];
    const float* L1v  = (const float*)d_in[7];
    const float* WS0  = (const float*)d_in[8];
    const float* WS1  = (const float*)d_in[9];
    const float* L2s  = (const float*)d_in[10];
    const float* L2v  = (const float*)d_in[11];
    float* out = (float*)d_out;
    char* ws = (char*)d_ws;

    unsigned short* Msg = (unsigned short*)ws;                 // 25,600,000
    unsigned short* Wc  = (unsigned short*)(ws + 25600000);    //     65,536
    unsigned short* WB0 = (unsigned short*)(ws + 25665536);    //     32,768
    unsigned short* WB1 = (unsigned short*)(ws + 25698304);    //     32,768
    int* off    = (int*)(ws + 25731072);                       //     40,004
    int* cursor = (int*)(ws + 25771076);                       //     40,000

    prep_kernel<<<65, 1024, 0, stream>>>(Wgen, L1s, L1v, WS0, WS1, L2s, L2v,
                                         edge_index, Wc, WB0, WB1, off, cursor);
    edge_kernel<<<512, 256, 0, stream>>>(node_feats, edge_attrs, edge_feats,
                                         edge_index, Wc, cursor, Msg);
    node_kernel<<<625, 256, 0, stream>>>(node_attrs, Msg, off, WB0, WB1, out);
}

// Round 10
// 142.206 us; speedup vs baseline: 1.1506x; 1.0151x over previous
//
#include <hip/hip_runtime.h>
#include <hip/hip_bf16.h>

#define N_NODES 10000
#define N_EDGES 100000

typedef __attribute__((ext_vector_type(8))) short short8;
typedef __attribute__((ext_vector_type(4))) short shortx4;
typedef __attribute__((ext_vector_type(4))) float f32x4;

static __device__ inline short bf16bits(float x) {
    union { __bf16 b; short s; } u;
    u.b = (__bf16)x;
    return u.s;
}
static __device__ inline unsigned short bf16u(float x) {
    union { __bf16 b; unsigned short s; } u;
    u.b = (__bf16)x;
    return u.s;
}
static __device__ inline float bf2f(unsigned short us) {
    union { unsigned int u; float f; } c;
    c.u = ((unsigned int)us) << 16;
    return c.f;
}
static __device__ inline short8 cvt8(const float* f) {
    short8 r;
#pragma unroll
    for (int j = 0; j < 8; ++j) r[j] = bf16bits(f[j]);
    return r;
}

// ---------------------------------------------------------------------------
// Combined prep kernel (unchanged from R9), 65 blocks x 1024 threads:
//  block 0:      LDS histogram (int4-batched) -> scan -> off/cursor
//  blocks 1..64: fold L1s/L1v -> Wc; fold L2s/L2v -> WB0/WB1 (bf16 B-frag)
// ---------------------------------------------------------------------------
__global__ __launch_bounds__(1024) void prep_kernel(
    const float* __restrict__ Wgen, const float* __restrict__ L1s,
    const float* __restrict__ L1v, const float* __restrict__ WS0,
    const float* __restrict__ WS1, const float* __restrict__ L2s,
    const float* __restrict__ L2v, const int* __restrict__ edge_index,
    unsigned short* __restrict__ Wc, unsigned short* __restrict__ WB0,
    unsigned short* __restrict__ WB1, int* __restrict__ off,
    int* __restrict__ cursor) {
    __shared__ int sdeg[N_NODES];   // 40 KB
    __shared__ int part[1024];      //  4 KB
    if (blockIdx.x == 0) {
        int t = threadIdx.x;
        for (int i = t; i < N_NODES; i += 1024) sdeg[i] = 0;
        __syncthreads();
        const int4* r4 = (const int4*)(edge_index + N_EDGES);
        for (int i0 = t; i0 < 24576; i0 += 4096) {
            int4 a = r4[i0];
            int4 b = r4[i0 + 1024];
            int4 c = r4[i0 + 2048];
            int4 d = r4[i0 + 3072];
            atomicAdd(&sdeg[a.x], 1); atomicAdd(&sdeg[a.y], 1);
            atomicAdd(&sdeg[a.z], 1); atomicAdd(&sdeg[a.w], 1);
            atomicAdd(&sdeg[b.x], 1); atomicAdd(&sdeg[b.y], 1);
            atomicAdd(&sdeg[b.z], 1); atomicAdd(&sdeg[b.w], 1);
            atomicAdd(&sdeg[c.x], 1); atomicAdd(&sdeg[c.y], 1);
            atomicAdd(&sdeg[c.z], 1); atomicAdd(&sdeg[c.w], 1);
            atomicAdd(&sdeg[d.x], 1); atomicAdd(&sdeg[d.y], 1);
            atomicAdd(&sdeg[d.z], 1); atomicAdd(&sdeg[d.w], 1);
        }
        if (t < 424) {
            int4 v = r4[24576 + t];
            atomicAdd(&sdeg[v.x], 1); atomicAdd(&sdeg[v.y], 1);
            atomicAdd(&sdeg[v.z], 1); atomicAdd(&sdeg[v.w], 1);
        }
        __syncthreads();
        int base = t * 10;
        int s = 0;
#pragma unroll
        for (int i = 0; i < 10; ++i) {
            int idx = base + i;
            if (idx < N_NODES) s += sdeg[idx];
        }
        part[t] = s;
        __syncthreads();
        for (int d = 1; d < 1024; d <<= 1) {
            int v = (t >= d) ? part[t - d] : 0;
            __syncthreads();
            part[t] += v;
            __syncthreads();
        }
        int run = part[t] - s;
#pragma unroll
        for (int i = 0; i < 10; ++i) {
            int idx = base + i;
            if (idx < N_NODES) {
                off[idx] = run;
                cursor[idx] = run;
                run += sdeg[idx];
            }
        }
        if (t == 1023) off[N_NODES] = run;
        return;
    }

    const float S = 1.0f / 128.0f;
    int tid = (blockIdx.x - 1) * 1024 + threadIdx.x;   // 0..65535
    if (tid < 32768) {
        int j = tid & 7;
        int lane = (tid >> 3) & 63;
        int ks = (tid >> 9) & 7;
        int nt = tid >> 12;
        int col = nt * 16 + (lane & 15);
        int u = (lane >> 4) * 8 + j;
        int r = ks;
        int p, c2;
        const float* M;
        float sc = S;
        if (col < 32)      { p = 0; M = L1s; c2 = col; }
        else if (col < 64) { p = 1; M = L1v; c2 = col - 32; }
        else if (col < 96) { p = 2; M = L1v; c2 = col - 64; }
        else               { p = 3; M = L1s; c2 = col - 96; sc = S * 0.57735026918962576f; }
        const float* wg = Wgen + r * 4096 + p * 1024 + u * 32;
        float acc = 0.f;
#pragma unroll
        for (int w = 0; w < 32; ++w) acc += wg[w] * M[w * 32 + c2];
        Wc[tid] = bf16u(acc * sc);
    } else {
        int idx = tid - 32768;
        int table = idx >> 14;
        int r14 = idx & 16383;
        int j = r14 & 7;
        int lane = (r14 >> 3) & 63;
        int ks = (r14 >> 9) & 15;
        int k = ks * 32 + (lane >> 4) * 8 + j;
        int u = k >> 4, v = k & 15;
        int w = ((r14 >> 13) & 1) * 16 + (lane & 15);
        const float* WS = table ? WS1 : WS0;
        const float* L2 = table ? L2v : L2s;
        const float* src = WS + u * 512 + v * 32;
        float acc = 0.f;
#pragma unroll
        for (int x = 0; x < 32; ++x) acc += src[x] * L2[x * 32 + w];
        unsigned short val = bf16u(acc * S);
        if (table) WB1[r14] = val; else WB0[r14] = val;
    }
}

// ---------------------------------------------------------------------------
// Edge kernel v6: pipelined tile loop + SHFL-FREE epilogue.
//  - slot published via LDS strip sSL[wave][16] (ds_write at loop top by
//    lanes<16, ds_read_b128 per lane in epilogue) — removes 20 dependent
//    bpermutes from the post-MFMA critical path.
//  - per-lane edge_attrs row loads (eaR[4]) issued at loop top, consumed in
//    epilogue — hidden behind the 96 MFMAs (R5's proven pattern).
// ---------------------------------------------------------------------------
__global__ __launch_bounds__(256) void edge_kernel(
    const float* __restrict__ node_feats, const float* __restrict__ edge_attrs,
    const float* __restrict__ edge_feats, const int* __restrict__ edge_index,
    const unsigned short* __restrict__ Wc, int* __restrict__ cursor,
    unsigned short* __restrict__ Msg) {
    __shared__ short8 sW8[4096];  // 64 KB, B-fragment order
    __shared__ int sSL[4][16];    // per-wave slot strip
    {
        const short8* src = (const short8*)Wc;
        for (int i = threadIdx.x; i < 4096; i += 256) sW8[i] = src[i];
    }
    __syncthreads();

    const int lane = threadIdx.x & 63;
    const int m = lane & 15, q = lane >> 4;
    const int wv = threadIdx.x >> 6;
    const int wave = (blockIdx.x * 256 + threadIdx.x) >> 6;
    const int stride = gridDim.x * 4;
    const int NT = N_EDGES / 16;

    int tile = wave;
    if (tile >= NT) return;

    float xsC[8], xvC[24], efC[8];
    f32x4 eaC;
    int slC = 0;

    {
        int e = tile * 16 + m;
        int snd = edge_index[e];
        if (lane < 16) slC = atomicAdd(&cursor[edge_index[N_EDGES + e]], 1);
        const float* g = node_feats + snd * 128;
        *(f32x4*)&xsC[0] = *(const f32x4*)(g + q * 8);
        *(f32x4*)&xsC[4] = *(const f32x4*)(g + q * 8 + 4);
#pragma unroll
        for (int i = 0; i < 6; ++i)
            *(f32x4*)&xvC[i * 4] = *(const f32x4*)(g + 32 + q * 24 + i * 4);
        *(f32x4*)&efC[0] = *(const f32x4*)(edge_feats + e * 8);
        *(f32x4*)&efC[4] = *(const f32x4*)(edge_feats + e * 8 + 4);
        eaC = *(const f32x4*)(edge_attrs + e * 4);
    }

    while (tile < NT) {
        const int tn = tile + stride;
        const bool hasN = tn < NT;

        // ---- publish current slots to LDS (read back in epilogue)
        if (lane < 16) sSL[wv][lane] = slC;

        // ---- per-lane epilogue-row attr loads (hidden behind MFMAs)
        f32x4 eaR[4];
#pragma unroll
        for (int t4 = 0; t4 < 4; ++t4)
            eaR[t4] = *(const f32x4*)(edge_attrs + (tile * 16 + q * 4 + t4) * 4);

        // ---- prefetch next tile's state
        float xsN[8], xvN[24], efN[8];
        f32x4 eaN;
        int slN = 0;
        if (hasN) {
            int en = tn * 16 + m;
            int sndN = edge_index[en];
            if (lane < 16) slN = atomicAdd(&cursor[edge_index[N_EDGES + en]], 1);
            const float* gN = node_feats + sndN * 128;
            *(f32x4*)&xsN[0] = *(const f32x4*)(gN + q * 8);
            *(f32x4*)&xsN[4] = *(const f32x4*)(gN + q * 8 + 4);
#pragma unroll
            for (int i = 0; i < 6; ++i)
                *(f32x4*)&xvN[i * 4] = *(const f32x4*)(gN + 32 + q * 24 + i * 4);
            *(f32x4*)&efN[0] = *(const f32x4*)(edge_feats + en * 8);
            *(f32x4*)&efN[4] = *(const f32x4*)(edge_feats + en * 8 + 4);
            eaN = *(const f32x4*)(edge_attrs + en * 4);
        }

        // ---- compute current tile
        float dt[8];
        {
            float y0 = eaC.y, y1 = eaC.z, y2 = eaC.w;
#pragma unroll
            for (int j = 0; j < 8; ++j)
                dt[j] = xvC[j * 3] * y0 + xvC[j * 3 + 1] * y1 + xvC[j * 3 + 2] * y2;
        }

        f32x4 z = {0.f, 0.f, 0.f, 0.f};
        f32x4 fA[2] = {z, z}, fB[2] = {z, z}, fD[2] = {z, z};
        f32x4 fC[3][2] = {{z, z}, {z, z}, {z, z}};

#pragma unroll
        for (int ks = 0; ks < 8; ++ks) {
            float h = efC[ks];
            float t[8];
#pragma unroll
            for (int j = 0; j < 8; ++j) t[j] = h * xsC[j];
            {
                short8 a = cvt8(t);
                fA[0] = __builtin_amdgcn_mfma_f32_16x16x32_bf16(a, sW8[(0 * 8 + ks) * 64 + lane], fA[0], 0, 0, 0);
                fA[1] = __builtin_amdgcn_mfma_f32_16x16x32_bf16(a, sW8[(1 * 8 + ks) * 64 + lane], fA[1], 0, 0, 0);
                fB[0] = __builtin_amdgcn_mfma_f32_16x16x32_bf16(a, sW8[(2 * 8 + ks) * 64 + lane], fB[0], 0, 0, 0);
                fB[1] = __builtin_amdgcn_mfma_f32_16x16x32_bf16(a, sW8[(3 * 8 + ks) * 64 + lane], fB[1], 0, 0, 0);
            }
            {
                short8 bc0 = sW8[(4 * 8 + ks) * 64 + lane];
                short8 bc1 = sW8[(5 * 8 + ks) * 64 + lane];
#pragma unroll
                for (int c = 0; c < 3; ++c) {
#pragma unroll
                    for (int j = 0; j < 8; ++j) t[j] = h * xvC[j * 3 + c];
                    short8 a = cvt8(t);
                    fC[c][0] = __builtin_amdgcn_mfma_f32_16x16x32_bf16(a, bc0, fC[c][0], 0, 0, 0);
                    fC[c][1] = __builtin_amdgcn_mfma_f32_16x16x32_bf16(a, bc1, fC[c][1], 0, 0, 0);
                }
            }
            {
#pragma unroll
                for (int j = 0; j < 8; ++j) t[j] = h * dt[j];
                short8 a = cvt8(t);
                fD[0] = __builtin_amdgcn_mfma_f32_16x16x32_bf16(a, sW8[(6 * 8 + ks) * 64 + lane], fD[0], 0, 0, 0);
                fD[1] = __builtin_amdgcn_mfma_f32_16x16x32_bf16(a, sW8[(7 * 8 + ks) * 64 + lane], fD[1], 0, 0, 0);
            }
        }

        // ---- epilogue: per-lane rows q*4+t4; slots via one ds_read_b128
        int4 sl4 = *(const int4*)&sSL[wv][q * 4];
        const int slR[4] = {sl4.x, sl4.y, sl4.z, sl4.w};
#pragma unroll
        for (int t4 = 0; t4 < 4; ++t4) {
            float ysr = eaR[t4].x, y0r = eaR[t4].y, y1r = eaR[t4].z, y2r = eaR[t4].w;
            int dr = slR[t4];
#pragma unroll
            for (int nt = 0; nt < 2; ++nt) {
                int col = nt * 16 + m;
                float pb = fB[nt][t4];
                shortx4 pk;
                pk[0] = bf16bits(ysr * fA[nt][t4] + fD[nt][t4]);
                pk[1] = bf16bits(y0r * pb + ysr * fC[0][nt][t4]);
                pk[2] = bf16bits(y1r * pb + ysr * fC[1][nt][t4]);
                pk[3] = bf16bits(y2r * pb + ysr * fC[2][nt][t4]);
                *(shortx4*)(Msg + (size_t)dr * 128 + col * 4) = pk;
            }
        }

        // ---- rotate pipeline
        tile = tn;
        if (hasN) {
#pragma unroll
            for (int j = 0; j < 8; ++j) { xsC[j] = xsN[j]; efC[j] = efN[j]; }
#pragma unroll
            for (int j = 0; j < 24; ++j) xvC[j] = xvN[j];
            eaC = eaN;
            slC = slN;
        }
    }
}

// ---------------------------------------------------------------------------
// Fused gather + node kernel; gather now 4x-batched (R8-histogram lesson:
// batch independent loads to cut serial latency hops; avg degree 10 -> 2-3
// iterations instead of 10).
// ---------------------------------------------------------------------------
__global__ __launch_bounds__(256) void node_kernel(
    const float* __restrict__ node_attrs, const unsigned short* __restrict__ Msg,
    const int* __restrict__ off, const unsigned short* __restrict__ WB0,
    const unsigned short* __restrict__ WB1, float* __restrict__ out) {
    __shared__ float sM[16][129];
    __shared__ float sAt[16][17];
    int n0 = blockIdx.x * 16;

    int nl = threadIdx.x >> 4;
    int cg = threadIdx.x & 15;
    int n = n0 + nl;
    int s0 = off[n], s1 = off[n + 1];
    float acc[8];
#pragma unroll
    for (int j = 0; j < 8; ++j) acc[j] = 0.f;
    int s = s0;
    for (; s + 3 < s1; s += 4) {
        f32x4 r0 = *(const f32x4*)(Msg + (size_t)(s + 0) * 128 + cg * 8);
        f32x4 r1 = *(const f32x4*)(Msg + (size_t)(s + 1) * 128 + cg * 8);
        f32x4 r2 = *(const f32x4*)(Msg + (size_t)(s + 2) * 128 + cg * 8);
        f32x4 r3 = *(const f32x4*)(Msg + (size_t)(s + 3) * 128 + cg * 8);
        const unsigned short* u0 = (const unsigned short*)&r0;
        const unsigned short* u1 = (const unsigned short*)&r1;
        const unsigned short* u2 = (const unsigned short*)&r2;
        const unsigned short* u3 = (const unsigned short*)&r3;
#pragma unroll
        for (int j = 0; j < 8; ++j)
            acc[j] += (bf2f(u0[j]) + bf2f(u1[j])) + (bf2f(u2[j]) + bf2f(u3[j]));
    }
    for (; s < s1; ++s) {
        f32x4 raw = *(const f32x4*)(Msg + (size_t)s * 128 + cg * 8);
        const unsigned short* us = (const unsigned short*)&raw;
#pragma unroll
        for (int j = 0; j < 8; ++j) acc[j] += bf2f(us[j]);
    }
#pragma unroll
    for (int j = 0; j < 8; ++j)
        sM[nl][(j & 3) * 32 + cg * 2 + (j >> 2)] = acc[j];
    sAt[nl][cg] = node_attrs[n * 16 + cg];
    __syncthreads();

    int p = threadIdx.x >> 6;
    int lane = threadIdx.x & 63;
    int m = lane & 15, q = lane >> 4;
    const unsigned short* WB = (p == 0) ? WB0 : WB1;
    int chb = p * 32;
    f32x4 z = {0.f, 0.f, 0.f, 0.f};
    f32x4 D0 = z, D1 = z;
#pragma unroll
    for (int ks = 0; ks < 16; ++ks) {
        int kb = ks * 32 + q * 8;
        float t[8];
#pragma unroll
        for (int j = 0; j < 8; ++j) {
            int k = kb + j;
            t[j] = sM[m][chb + (k >> 4)] * sAt[m][k & 15];
        }
        short8 a = cvt8(t);
        short8 b0 = *(const short8*)(WB + (ks * 64 + lane) * 8);
        short8 b1 = *(const short8*)(WB + ((16 + ks) * 64 + lane) * 8);
        D0 = __builtin_amdgcn_mfma_f32_16x16x32_bf16(a, b0, D0, 0, 0, 0);
        D1 = __builtin_amdgcn_mfma_f32_16x16x32_bf16(a, b1, D1, 0, 0, 0);
    }

#pragma unroll
    for (int t4 = 0; t4 < 4; ++t4) {
        int nl2 = q * 4 + t4;
        int nn = n0 + nl2;
        if (p == 0) {
            out[nn * 128 + m]      = sM[nl2][m] + D0[t4];
            out[nn * 128 + 16 + m] = sM[nl2][16 + m] + D1[t4];
        } else {
            int i = p - 1;
            out[nn * 128 + 32 + m * 3 + i]        = sM[nl2][chb + m] + D0[t4];
            out[nn * 128 + 32 + (16 + m) * 3 + i] = sM[nl2][chb + 16 + m] + D1[t4];
        }
    }
}

extern "C" void kernel_launch(void* const* d_in, const int* in_sizes, int n_in,
                              void* d_out, int out_size, void* d_ws, size_t ws_size,
                              hipStream_t stream) {
    (void)in_sizes; (void)n_in; (void)out_size; (void)ws_size;
    const float* node_attrs = (const float*)d_in[0];
    const float* node_feats = (const float*)d_in[1];
    const float* edge_attrs = (const float*)d_in[2];
    const float* edge_feats = (const float*)d_in[3];
    const int*   edge_index = (const int*)d_in[4];
    const float* Wgen = (const float*)d_in[5];
    const float* L1s  = (const float*)d_in[6];
    const float* L1v  = (const float*)d_in[7];
    const float* WS0  = (const float*)d_in[8];
    const float* WS1  = (const float*)d_in[9];
    const float* L2s  = (const float*)d_in[10];
    const float* L2v  = (const float*)d_in[11];
    float* out = (float*)d_out;
    char* ws = (char*)d_ws;

    unsigned short* Msg = (unsigned short*)ws;                 // 25,600,000
    unsigned short* Wc  = (unsigned short*)(ws + 25600000);    //     65,536
    unsigned short* WB0 = (unsigned short*)(ws + 25665536);    //     32,768
    unsigned short* WB1 = (unsigned short*)(ws + 25698304);    //     32,768
    int* off    = (int*)(ws + 25731072);                       //     40,004
    int* cursor = (int*)(ws + 25771076);                       //     40,000

    prep_kernel<<<65, 1024, 0, stream>>>(Wgen, L1s, L1v, WS0, WS1, L2s, L2v,
                                         edge_index, Wc, WB0, WB1, off, cursor);
    edge_kernel<<<512, 256, 0, stream>>>(node_feats, edge_attrs, edge_feats,
                                         edge_index, Wc, cursor, Msg);
    node_kernel<<<625, 256, 0, stream>>>(node_attrs, Msg, off, WB0, WB1, out);
}